// Round 6
// baseline (247.076 us; speedup 1.0000x reference)
//
#include <hip/hip_runtime.h>
#include <math.h>

typedef __attribute__((ext_vector_type(8))) short short8;
typedef __attribute__((ext_vector_type(4))) float f32x4;

__device__ __forceinline__ short f2bf(float f) {
    union { float f; unsigned u; } v; v.f = f;
    unsigned r = v.u + 0x7fff + ((v.u >> 16) & 1);
    return (short)(r >> 16);
}

// async global->LDS, 16B per lane; lds base must be wave-uniform.
__device__ __forceinline__ void gload16(const short* g, short* l) {
    __builtin_amdgcn_global_load_lds(
        (const __attribute__((address_space(1))) unsigned int*)g,
        (__attribute__((address_space(3))) unsigned int*)l,
        16, 0, 0);
}

// ---------------------------------------------------------------------------
// prep: x->bf16 (blocks 0..2047), weight transposes (2048..5119), bias pack.
// ---------------------------------------------------------------------------
__global__ __launch_bounds__(256) void prep_kernel(
    const float* __restrict__ x, short* __restrict__ xb,
    const float* __restrict__ Wq, const float* __restrict__ Wk,
    const float* __restrict__ Wv, const float* __restrict__ Wo,
    const float* __restrict__ W1, const float* __restrict__ W2,
    short* __restrict__ Wqkv_t, short* __restrict__ Wo_t,
    short* __restrict__ W1_t, short* __restrict__ W2_t,
    const float* __restrict__ bq, const float* __restrict__ bk,
    const float* __restrict__ bv, float* __restrict__ qbias)
{
    int bid = blockIdx.x;
    if (bid < 2048) {
        int i = (bid * 256 + threadIdx.x) * 4;
        float4 v = *reinterpret_cast<const float4*>(&x[i]);
        short4 o;
        o.x = f2bf(v.x); o.y = f2bf(v.y); o.z = f2bf(v.z); o.w = f2bf(v.w);
        *reinterpret_cast<short4*>(&xb[i]) = o;
        return;
    }
    if (bid < 5120) {
        int t = bid - 2048;
        const float* W; short* Wt; int K, N, nbx, loc;
        if (t < 1024) {
            int j = t >> 8; loc = t & 255; K = 512; N = 512; nbx = 16;
            W  = (j == 0) ? Wq : (j == 1) ? Wk : (j == 2) ? Wv : Wo;
            Wt = (j == 0) ? Wqkv_t : (j == 1) ? Wqkv_t + 512 * 512
               : (j == 2) ? Wqkv_t + 1024 * 512 : Wo_t;
        } else if (t < 2048) {
            loc = t - 1024; W = W1; Wt = W1_t; K = 512; N = 2048; nbx = 16;
        } else {
            loc = t - 2048; W = W2; Wt = W2_t; K = 2048; N = 512; nbx = 64;
        }
        int k0 = (loc % nbx) * 32, n0 = (loc / nbx) * 32;
        __shared__ float tl[32][33];
        int tx = threadIdx.x & 31, ty = threadIdx.x >> 5;
#pragma unroll
        for (int r = ty; r < 32; r += 8)
            tl[r][tx] = W[(size_t)(k0 + r) * N + n0 + tx];
        __syncthreads();
#pragma unroll
        for (int r = ty; r < 32; r += 8)
            Wt[(size_t)(n0 + r) * K + k0 + tx] = f2bf(tl[tx][r]);
        return;
    }
    {
        int i = (bid - 5120) * 256 + threadIdx.x;
        if (i < 1536)
            qbias[i] = (i < 512) ? bq[i] : (i < 1024 ? bk[i - 512] : bv[i - 1024]);
    }
}

// ---------------------------------------------------------------------------
// Score-only streaming body: block (hb, si) writes heat tiles tt = si+1..31
// for its 64 s-rows. Pure streaming: no LDS, no barriers.
// ---------------------------------------------------------------------------
__device__ __forceinline__ void scores_body(
    const short* __restrict__ QKV, float* __restrict__ heat, int hb, int si)
{
    constexpr int S = 2048, LD = 1536;
    int tid = threadIdx.x, wid = tid >> 6, lane = tid & 63;
    int g = lane >> 4, c = lane & 15, g4 = g * 4;
    int h = hb >> 1, b = hb & 1;
    int sglob = si * 64 + wid * 16 + c;
    const short* qp = QKV + (size_t)(b * S + sglob) * LD + h * 64 + g * 8;
    short8 q0 = *(const short8*)qp, q1 = *(const short8*)(qp + 32);
    const short* kb_base = QKV + (size_t)b * S * LD + 512 + h * 64;

    short8 kcur[4][2];
#pragma unroll
    for (int ni = 0; ni < 4; ++ni)
#pragma unroll
        for (int kc = 0; kc < 2; ++kc)
            kcur[ni][kc] = *(const short8*)(kb_base +
                (size_t)((si + 1) * 64 + ni * 16 + c) * LD + kc * 32 + g * 8);

    for (int tt = si + 1; tt < 32; ++tt) {
        short8 knext[4][2];
        if (tt < 31) {
#pragma unroll
            for (int ni = 0; ni < 4; ++ni)
#pragma unroll
                for (int kc = 0; kc < 2; ++kc)
                    knext[ni][kc] = *(const short8*)(kb_base +
                        (size_t)((tt + 1) * 64 + ni * 16 + c) * LD + kc * 32 + g * 8);
        }
        f32x4 sacc[4];
#pragma unroll
        for (int ni = 0; ni < 4; ++ni) {
            sacc[ni] = (f32x4){0.f, 0.f, 0.f, 0.f};
            sacc[ni] = __builtin_amdgcn_mfma_f32_16x16x32_bf16(kcur[ni][0], q0, sacc[ni], 0, 0, 0);
            sacc[ni] = __builtin_amdgcn_mfma_f32_16x16x32_bf16(kcur[ni][1], q1, sacc[ni], 0, 0, 0);
        }
#pragma unroll
        for (int ni = 0; ni < 4; ++ni)
            __builtin_nontemporal_store(sacc[ni],
                (f32x4*)&heat[((size_t)hb * S + sglob) * S + tt * 64 + ni * 16 + g4]);
        if (tt < 31) {
#pragma unroll
            for (int ni = 0; ni < 4; ++ni)
#pragma unroll
                for (int kc = 0; kc < 2; ++kc)
                    kcur[ni][kc] = knext[ni][kc];
        }
    }
}

__global__ __launch_bounds__(256) void scores_kernel(
    const short* __restrict__ QKV, float* __restrict__ heat)
{
    int s = blockIdx.x;               // 0..495
    scores_body(QKV, heat, s / 31, s % 31);
}

// ---------------------------------------------------------------------------
// GEMM body, double-buffered LDS (T3-min): stage(next) issued before compute,
// one vmcnt(0)+barrier per K-iter (compiler emits drain at __syncthreads).
// BM = MI*32, BN = NI*32, BK = 64, 4 waves (2x2).
// ---------------------------------------------------------------------------
template<int MI, int NI>
__device__ __forceinline__ void gemm_body(
    short* __restrict__ smem,
    const short* __restrict__ A, int lda,
    const short* __restrict__ Bt, int ldb,
    const float* __restrict__ bias, const float* __restrict__ resid,
    float* __restrict__ Cf, short* __restrict__ Cb,
    int N, int K, int relu, int bx, int byy)
{
    constexpr int BM = MI * 32, BN = NI * 32;
    constexpr int ASZ = BM * 64, BSZ = BN * 64;
    int tid = threadIdx.x, wid = tid >> 6, lane = tid & 63;
    int g = lane >> 4, c = lane & 15;
    int wm = wid >> 1, wn = wid & 1;
    size_t m0 = (size_t)bx * BM, n0 = (size_t)byy * BN;
    int lrow = lane >> 3, lcol = (lane & 7) * 8;

    f32x4 acc[MI][NI];
#pragma unroll
    for (int i = 0; i < MI; ++i)
#pragma unroll
        for (int j = 0; j < NI; ++j)
            acc[i][j] = (f32x4){0.f, 0.f, 0.f, 0.f};

    auto stage = [&](int buf, int k0) {
        short* Ab = smem + buf * ASZ;
        short* Bb = smem + 2 * ASZ + buf * BSZ;
#pragma unroll
        for (int i = 0; i < MI; ++i) {
            int chunk = wid * MI + i; int row = chunk * 8 + lrow;
            gload16(A + (m0 + row) * lda + k0 + lcol, Ab + chunk * 512);
        }
#pragma unroll
        for (int i = 0; i < NI; ++i) {
            int chunk = wid * NI + i; int row = chunk * 8 + lrow;
            gload16(Bt + (n0 + row) * ldb + k0 + lcol, Bb + chunk * 512);
        }
    };

    int nt = K >> 6;
    stage(0, 0);
    __syncthreads();
    int cur = 0;
    for (int t = 0; t < nt; ++t) {
        if (t + 1 < nt) stage(cur ^ 1, (t + 1) * 64);
        const short* Ab = smem + cur * ASZ;
        const short* Bb = smem + 2 * ASZ + cur * BSZ;
        short8 a[MI][2], b[NI][2];
#pragma unroll
        for (int kc = 0; kc < 2; ++kc) {
#pragma unroll
            for (int mi = 0; mi < MI; ++mi)
                a[mi][kc] = *(const short8*)&Ab[(wm * MI * 16 + mi * 16 + c) * 64 + kc * 32 + g * 8];
#pragma unroll
            for (int ni = 0; ni < NI; ++ni)
                b[ni][kc] = *(const short8*)&Bb[(wn * NI * 16 + ni * 16 + c) * 64 + kc * 32 + g * 8];
        }
#pragma unroll
        for (int kc = 0; kc < 2; ++kc)
#pragma unroll
            for (int mi = 0; mi < MI; ++mi)
#pragma unroll
                for (int ni = 0; ni < NI; ++ni)
                    acc[mi][ni] = __builtin_amdgcn_mfma_f32_16x16x32_bf16(
                        a[mi][kc], b[ni][kc], acc[mi][ni], 0, 0, 0);
        if (t + 1 < nt) { __syncthreads(); cur ^= 1; }
    }

#pragma unroll
    for (int mi = 0; mi < MI; ++mi)
#pragma unroll
        for (int ni = 0; ni < NI; ++ni)
#pragma unroll
            for (int r = 0; r < 4; ++r) {
                size_t m = m0 + wm * (MI * 16) + mi * 16 + g * 4 + r;
                size_t n = n0 + wn * (NI * 16) + ni * 16 + c;
                float v = acc[mi][ni][r];
                if (bias)  v += bias[n];
                if (resid) v += resid[m * N + n];
                if (relu)  v = fmaxf(v, 0.f);
                if (Cf) Cf[m * N + n] = v;
                if (Cb) Cb[m * N + n] = f2bf(v);
            }
}

// ---------------------------------------------------------------------------
// Combined GEMM + embedded score-streaming blocks (1D grid).
// blocks [0, ngemm): GEMM tile (id%gx, id/gx); [ngemm, ...): scores (hb0+, si)
// ---------------------------------------------------------------------------
template<int MI, int NI>
__global__ __launch_bounds__(256) void gemm_sc(
    const short* __restrict__ A, int lda,
    const short* __restrict__ Bt, int ldb,
    const float* __restrict__ bias, const float* __restrict__ resid,
    float* __restrict__ Cf, short* __restrict__ Cb,
    int N, int K, int relu, int gx, int ngemm,
    const short* __restrict__ QKV, float* __restrict__ heat, int hb0)
{
    __shared__ short smem[2 * (MI + NI) * 32 * 64];
    int id = blockIdx.x;
    if (id < ngemm) {
        gemm_body<MI, NI>(smem, A, lda, Bt, ldb, bias, resid, Cf, Cb,
                          N, K, relu, id % gx, id / gx);
    } else {
        int s = id - ngemm;            // 0..247
        scores_body(QKV, heat, hb0 + s / 31, s % 31);
    }
}

// ---------------------------------------------------------------------------
// Causal flash attention: block handles s-block `by`, tiles 0..by only.
// 1 barrier/tile (V double-buffered), V reg-prefetch 1 tile ahead, K reg
// prefetch, mask only on diagonal tile. Pairing: blocks id and id+256 share
// (hb,q) with by = 31-q / q -> per-CU work balanced at 33 tiles.
// ---------------------------------------------------------------------------
__global__ __launch_bounds__(256) void attn_causal(
    const short* __restrict__ QKV, float* __restrict__ heat,
    short* __restrict__ wv)
{
    constexpr int S = 2048, LD = 1536;
    __shared__ short Vt[2][64][72];    // [buf][v][t]
    __shared__ short Pl[4][16][72];    // per-wave P, [s][t]

    int tid = threadIdx.x, wid = tid >> 6, lane = tid & 63;
    int g = lane >> 4, c = lane & 15, g4 = g * 4;
    int id = blockIdx.x;
    int lo = id & 255;
    int hb = lo >> 4, qq = lo & 15;
    int by = (id < 256) ? (31 - qq) : qq;
    int h = hb >> 1, b = hb & 1;
    int s0 = by * 64, sbase = s0 + wid * 16, sglob = sbase + c;

    const short* qp = QKV + (size_t)(b * S + sglob) * LD + h * 64 + g * 8;
    short8 q0 = *(const short8*)qp, q1 = *(const short8*)(qp + 32);

    f32x4 o[4];
#pragma unroll
    for (int ni = 0; ni < 4; ++ni) o[ni] = (f32x4){0.f, 0.f, 0.f, 0.f};
    float m_run = -1e30f, l_run = 0.f;

    const short* kb_base = QKV + (size_t)b * S * LD + 512 + h * 64;
    int vrow = tid >> 2, vch = tid & 3;
    const short* vb_base = QKV + (size_t)b * S * LD + 1024 + h * 64 + vch * 16;

    short8 kcur[4][2];
#pragma unroll
    for (int ni = 0; ni < 4; ++ni)
#pragma unroll
        for (int kc = 0; kc < 2; ++kc)
            kcur[ni][kc] = *(const short8*)(kb_base +
                (size_t)(ni * 16 + c) * LD + kc * 32 + g * 8);
    short8 va, vb2;
    {
        const short* vp = vb_base + (size_t)vrow * LD;
        va = *(const short8*)vp; vb2 = *(const short8*)(vp + 8);
    }

    for (int tt = 0; tt <= by; ++tt) {
        int cur = tt & 1;
        // write V(tt) regs -> LDS (safe: last reader of this buf drained
        // before the previous iteration's barrier)
#pragma unroll
        for (int j = 0; j < 8; ++j) Vt[cur][vch * 16 + j][vrow] = va[j];
#pragma unroll
        for (int j = 0; j < 8; ++j) Vt[cur][vch * 16 + 8 + j][vrow] = vb2[j];

        short8 knext[4][2], vna, vnb;
        if (tt < by) {    // issue next-tile loads early (hide under compute)
            const short* vp = vb_base + (size_t)((tt + 1) * 64 + vrow) * LD;
            vna = *(const short8*)vp; vnb = *(const short8*)(vp + 8);
#pragma unroll
            for (int ni = 0; ni < 4; ++ni)
#pragma unroll
                for (int kc = 0; kc < 2; ++kc)
                    knext[ni][kc] = *(const short8*)(kb_base +
                        (size_t)((tt + 1) * 64 + ni * 16 + c) * LD + kc * 32 + g * 8);
        }

        int t0 = tt * 64;
        f32x4 sacc[4];
#pragma unroll
        for (int ni = 0; ni < 4; ++ni) {
            sacc[ni] = (f32x4){0.f, 0.f, 0.f, 0.f};
            sacc[ni] = __builtin_amdgcn_mfma_f32_16x16x32_bf16(kcur[ni][0], q0, sacc[ni], 0, 0, 0);
            sacc[ni] = __builtin_amdgcn_mfma_f32_16x16x32_bf16(kcur[ni][1], q1, sacc[ni], 0, 0, 0);
        }
#pragma unroll
        for (int ni = 0; ni < 4; ++ni)
            __builtin_nontemporal_store(sacc[ni],
                (f32x4*)&heat[((size_t)hb * S + sglob) * S + t0 + ni * 16 + g4]);

        float tm = -1e30f;
        if (tt == by) {   // diagonal: mask
#pragma unroll
            for (int ni = 0; ni < 4; ++ni)
#pragma unroll
                for (int r = 0; r < 4; ++r) {
                    int t = t0 + ni * 16 + g4 + r;
                    float v = (t <= sglob) ? sacc[ni][r] : -1e30f;
                    sacc[ni][r] = v;
                    tm = fmaxf(tm, v);
                }
        } else {          // interior: fully causal, no mask
#pragma unroll
            for (int ni = 0; ni < 4; ++ni)
#pragma unroll
                for (int r = 0; r < 4; ++r)
                    tm = fmaxf(tm, sacc[ni][r]);
        }
        tm = fmaxf(tm, __shfl_xor(tm, 16));
        tm = fmaxf(tm, __shfl_xor(tm, 32));

        float mn = fmaxf(m_run, tm);
        float sc = __expf(m_run - mn);
        m_run = mn;
        float ps = 0.f;
#pragma unroll
        for (int ni = 0; ni < 4; ++ni)
#pragma unroll
            for (int r = 0; r < 4; ++r) {
                float p = __expf(sacc[ni][r] - mn);
                sacc[ni][r] = p;
                ps += p;
            }
        ps += __shfl_xor(ps, 16);
        ps += __shfl_xor(ps, 32);
        l_run = l_run * sc + ps;

        float scr[4];
#pragma unroll
        for (int r = 0; r < 4; ++r) scr[r] = __shfl(sc, g4 + r, 64);
#pragma unroll
        for (int ni = 0; ni < 4; ++ni)
#pragma unroll
            for (int r = 0; r < 4; ++r)
                o[ni][r] *= scr[r];

        // P (bf16) to wave-local LDS: lane owns row s=c, contiguous t
#pragma unroll
        for (int ni = 0; ni < 4; ++ni) {
            short4 pw;
            pw.x = f2bf(sacc[ni][0]); pw.y = f2bf(sacc[ni][1]);
            pw.z = f2bf(sacc[ni][2]); pw.w = f2bf(sacc[ni][3]);
            *reinterpret_cast<short4*>(&Pl[wid][c][ni * 16 + g4]) = pw;
        }

        __syncthreads();   // Vt[cur] fully written by all waves

        short8 pa0 = *reinterpret_cast<const short8*>(&Pl[wid][c][g * 8]);
        short8 pa1 = *reinterpret_cast<const short8*>(&Pl[wid][c][32 + g * 8]);
#pragma unroll
        for (int ni = 0; ni < 4; ++ni) {
            short8 vb0 = *reinterpret_cast<const short8*>(&Vt[cur][ni * 16 + c][g * 8]);
            short8 vb1 = *reinterpret_cast<const short8*>(&Vt[cur][ni * 16 + c][32 + g * 8]);
            o[ni] = __builtin_amdgcn_mfma_f32_16x16x32_bf16(pa0, vb0, o[ni], 0, 0, 0);
            o[ni] = __builtin_amdgcn_mfma_f32_16x16x32_bf16(pa1, vb1, o[ni], 0, 0, 0);
        }

        if (tt < by) {
#pragma unroll
            for (int ni = 0; ni < 4; ++ni)
#pragma unroll
                for (int kc = 0; kc < 2; ++kc)
                    kcur[ni][kc] = knext[ni][kc];
            va = vna; vb2 = vnb;
        }
    }

    float linv[4];
#pragma unroll
    for (int r = 0; r < 4; ++r) linv[r] = 1.0f / __shfl(l_run, g4 + r, 64);
#pragma unroll
    for (int ni = 0; ni < 4; ++ni)
#pragma unroll
        for (int r = 0; r < 4; ++r) {
            float v = o[ni][r] * linv[r];
            wv[(size_t)(b * S + sbase + g4 + r) * 512 + h * 64 + ni * 16 + c] = f2bf(v);
        }
}

// ---------------------------------------------------------------------------
// LayerNorm over last dim 512; optional secondary bf16 output.
// ---------------------------------------------------------------------------
__device__ __forceinline__ float block_sum256(float v, float* sm) {
#pragma unroll
    for (int off = 32; off; off >>= 1) v += __shfl_down(v, off);
    __syncthreads();
    if ((threadIdx.x & 63) == 0) sm[threadIdx.x >> 6] = v;
    __syncthreads();
    return sm[0] + sm[1] + sm[2] + sm[3];
}

__global__ __launch_bounds__(256) void ln_kernel(
    const float* __restrict__ in, const float* __restrict__ g,
    const float* __restrict__ bta, float* __restrict__ outf,
    short* __restrict__ outb)
{
    __shared__ float sm[4];
    int row = blockIdx.x, tid = threadIdx.x;
    const float* r = in + (size_t)row * 512;
    float v0 = r[tid], v1 = r[tid + 256];
    float mu = block_sum256(v0 + v1, sm) * (1.f / 512.f);
    float d0 = v0 - mu, d1 = v1 - mu;
    float var = block_sum256(d0 * d0 + d1 * d1, sm) * (1.f / 512.f);
    float rs = rsqrtf(var + 1e-5f);
    float o0 = d0 * rs * g[tid] + bta[tid];
    float o1 = d1 * rs * g[tid + 256] + bta[tid + 256];
    outf[(size_t)row * 512 + tid]       = o0;
    outf[(size_t)row * 512 + tid + 256] = o1;
    if (outb) {
        outb[(size_t)row * 512 + tid]       = f2bf(o0);
        outb[(size_t)row * 512 + tid + 256] = f2bf(o1);
    }
}

// ---------------------------------------------------------------------------
extern "C" void kernel_launch(void* const* d_in, const int* in_sizes, int n_in,
                              void* d_out, int out_size, void* d_ws, size_t ws_size,
                              hipStream_t stream)
{
    const float* x    = (const float*)d_in[0];
    const float* Wq   = (const float*)d_in[1];
    const float* bq   = (const float*)d_in[2];
    const float* Wk   = (const float*)d_in[3];
    const float* bk   = (const float*)d_in[4];
    const float* Wv   = (const float*)d_in[5];
    const float* bv   = (const float*)d_in[6];
    const float* Wo   = (const float*)d_in[7];
    const float* bo   = (const float*)d_in[8];
    const float* W1   = (const float*)d_in[9];
    const float* b1   = (const float*)d_in[10];
    const float* W2   = (const float*)d_in[11];
    const float* b2   = (const float*)d_in[12];
    const float* ln1g = (const float*)d_in[13];
    const float* ln1b = (const float*)d_in[14];
    const float* ln2g = (const float*)d_in[15];
    const float* ln2b = (const float*)d_in[16];

    const int T = 4096;

    char* w = (char*)d_ws;
    short* xb     = (short*)(w);                     // 4096x512 bf16
    short* QKVb   = (short*)(w + 4194304);           // 4096x1536 bf16 (live until FFN1 done)
    short* wvb    = (short*)(w + 16777216);          // 4096x512 bf16
    float* tmpf   = (float*)(w + 20971520);          // 4096x512 f32
    float* x1f    = (float*)(w + 29360128);          // 4096x512 f32
    short* x1b    = (short*)(w + 37748736);          // 4096x512 bf16
    short* Wqkv_t = (short*)(w + 41943040);          // 1536x512 bf16
    short* Wo_t   = (short*)(w + 43515904);          // 512x512 bf16
    short* W1_t   = (short*)(w + 44040192);          // 2048x512 bf16
    short* W2_t   = (short*)(w + 46137344);          // 512x2048 bf16
    float* qbias  = (float*)(w + 48234496);          // 1536 f32

    // Overlapped scheme needs hidb (16MB) disjoint from QKVb -> ws >= 64MB.
    bool big = ws_size >= (size_t)67108864;
    short* hidb = big ? (short*)(w + 50331648)       // [48M, 64M)
                      : (short*)(w);                 // fallback: alias xb+QKVb

    float* out_x2 = (float*)d_out;
    float* heat   = out_x2 + (size_t)T * 512;

    prep_kernel<<<dim3(5126), 256, 0, stream>>>(
        x, xb, Wq, Wk, Wv, Wo, W1, W2,
        Wqkv_t, Wo_t, W1_t, W2_t, bq, bk, bv, qbias);

    // QKV projection (combined, N=1536)
    gemm_sc<2, 4><<<dim3(768), 256, 0, stream>>>(
        xb, 512, Wqkv_t, 512, qbias, nullptr, nullptr, QKVb,
        1536, 512, 0, 64, 768, nullptr, nullptr, 0);

    // causal flash attention (writes causal heat tiles + wv)
    attn_causal<<<dim3(512), 256, 0, stream>>>(QKVb, heat, wvb);

    if (!big)   // fallback: stream the score-only tiles standalone
        scores_kernel<<<dim3(496), 256, 0, stream>>>(QKVb, heat);

    // Wo projection + residual (+ scores hb 0..7 overlapped)
    gemm_sc<2, 2><<<dim3(big ? 760 : 512), 256, 0, stream>>>(
        wvb, 512, Wo_t, 512, bo, x, tmpf, nullptr,
        512, 512, 0, 64, 512, big ? QKVb : nullptr, heat, 0);
    ln_kernel<<<dim3(T), 256, 0, stream>>>(tmpf, ln1g, ln1b, x1f, x1b);

    // FFN1 (+ scores hb 8..15 overlapped)
    gemm_sc<2, 4><<<dim3(big ? 1272 : 1024), 256, 0, stream>>>(
        x1b, 512, W1_t, 512, b1, nullptr, nullptr, hidb,
        2048, 512, 1, 64, 1024, big ? QKVb : nullptr, heat, 8);

    // FFN2 + residual
    gemm_sc<2, 2><<<dim3(512), 256, 0, stream>>>(
        hidb, 2048, W2_t, 2048, b2, x1f, tmpf, nullptr,
        512, 2048, 0, 64, 512, nullptr, nullptr, 0);
    ln_kernel<<<dim3(T), 256, 0, stream>>>(tmpf, ln2g, ln2b, out_x2, nullptr);
}

// Round 7
// 227.363 us; speedup vs baseline: 1.0867x; 1.0867x over previous
//
#include <hip/hip_runtime.h>
#include <math.h>

typedef __attribute__((ext_vector_type(8))) short short8;
typedef __attribute__((ext_vector_type(4))) float f32x4;

__device__ __forceinline__ short f2bf(float f) {
    union { float f; unsigned u; } v; v.f = f;
    unsigned r = v.u + 0x7fff + ((v.u >> 16) & 1);
    return (short)(r >> 16);
}

// async global->LDS, 16B per lane; lds base must be wave-uniform.
__device__ __forceinline__ void gload16(const short* g, short* l) {
    __builtin_amdgcn_global_load_lds(
        (const __attribute__((address_space(1))) unsigned int*)g,
        (__attribute__((address_space(3))) unsigned int*)l,
        16, 0, 0);
}

// ---------------------------------------------------------------------------
// prep: x->bf16 (blocks 0..2047), weight transposes (2048..5119), bias pack.
// ---------------------------------------------------------------------------
__global__ __launch_bounds__(256) void prep_kernel(
    const float* __restrict__ x, short* __restrict__ xb,
    const float* __restrict__ Wq, const float* __restrict__ Wk,
    const float* __restrict__ Wv, const float* __restrict__ Wo,
    const float* __restrict__ W1, const float* __restrict__ W2,
    short* __restrict__ Wqkv_t, short* __restrict__ Wo_t,
    short* __restrict__ W1_t, short* __restrict__ W2_t,
    const float* __restrict__ bq, const float* __restrict__ bk,
    const float* __restrict__ bv, float* __restrict__ qbias)
{
    int bid = blockIdx.x;
    if (bid < 2048) {
        int i = (bid * 256 + threadIdx.x) * 4;
        float4 v = *reinterpret_cast<const float4*>(&x[i]);
        short4 o;
        o.x = f2bf(v.x); o.y = f2bf(v.y); o.z = f2bf(v.z); o.w = f2bf(v.w);
        *reinterpret_cast<short4*>(&xb[i]) = o;
        return;
    }
    if (bid < 5120) {
        int t = bid - 2048;
        const float* W; short* Wt; int K, N, nbx, loc;
        if (t < 1024) {
            int j = t >> 8; loc = t & 255; K = 512; N = 512; nbx = 16;
            W  = (j == 0) ? Wq : (j == 1) ? Wk : (j == 2) ? Wv : Wo;
            Wt = (j == 0) ? Wqkv_t : (j == 1) ? Wqkv_t + 512 * 512
               : (j == 2) ? Wqkv_t + 1024 * 512 : Wo_t;
        } else if (t < 2048) {
            loc = t - 1024; W = W1; Wt = W1_t; K = 512; N = 2048; nbx = 16;
        } else {
            loc = t - 2048; W = W2; Wt = W2_t; K = 2048; N = 512; nbx = 64;
        }
        int k0 = (loc % nbx) * 32, n0 = (loc / nbx) * 32;
        __shared__ float tl[32][33];
        int tx = threadIdx.x & 31, ty = threadIdx.x >> 5;
#pragma unroll
        for (int r = ty; r < 32; r += 8)
            tl[r][tx] = W[(size_t)(k0 + r) * N + n0 + tx];
        __syncthreads();
#pragma unroll
        for (int r = ty; r < 32; r += 8)
            Wt[(size_t)(n0 + r) * K + k0 + tx] = f2bf(tl[tx][r]);
        return;
    }
    {
        int i = (bid - 5120) * 256 + threadIdx.x;
        if (i < 1536)
            qbias[i] = (i < 512) ? bq[i] : (i < 1024 ? bk[i - 512] : bv[i - 1024]);
    }
}

// ---------------------------------------------------------------------------
// bf16 MFMA GEMM (R5 structure: single-buffered, 2 barriers/K-iter).
// BM = MI*32, BN = NI*32, BK = 64, 4 waves (2x2), global_load_lds staging.
// ---------------------------------------------------------------------------
template<int MI, int NI>
__global__ __launch_bounds__(256) void gemm2(
    const short* __restrict__ A, int lda,
    const short* __restrict__ Bt, int ldb,
    const float* __restrict__ bias,
    const float* __restrict__ resid,
    float* __restrict__ Cf, short* __restrict__ Cb,
    int N, int K, int relu)
{
    constexpr int BM = MI * 32;
    constexpr int BN = NI * 32;
    __shared__ short Ash[BM * 64];
    __shared__ short Bsh[BN * 64];
    int tid = threadIdx.x;
    int wid = tid >> 6, lane = tid & 63;
    int g = lane >> 4, c = lane & 15;
    int wm = wid >> 1, wn = wid & 1;
    size_t m0 = (size_t)blockIdx.x * BM;
    size_t n0 = (size_t)blockIdx.y * BN;
    int lrow = lane >> 3;          // 0..7
    int lcol = (lane & 7) * 8;     // shorts (16B granule)

    f32x4 acc[MI][NI];
#pragma unroll
    for (int i = 0; i < MI; ++i)
#pragma unroll
        for (int j = 0; j < NI; ++j)
            acc[i][j] = (f32x4){0.f, 0.f, 0.f, 0.f};

    for (int k0 = 0; k0 < K; k0 += 64) {
        __syncthreads();
#pragma unroll
        for (int i = 0; i < MI; ++i) {
            int chunk = wid * MI + i; int row = chunk * 8 + lrow;
            gload16(A + (m0 + row) * lda + k0 + lcol, Ash + chunk * 512);
        }
#pragma unroll
        for (int i = 0; i < NI; ++i) {
            int chunk = wid * NI + i; int row = chunk * 8 + lrow;
            gload16(Bt + (n0 + row) * ldb + k0 + lcol, Bsh + chunk * 512);
        }
        __syncthreads();

        short8 a[MI][2], b[NI][2];
#pragma unroll
        for (int kc = 0; kc < 2; ++kc) {
#pragma unroll
            for (int mi = 0; mi < MI; ++mi)
                a[mi][kc] = *(const short8*)&Ash[(wm * MI * 16 + mi * 16 + c) * 64 + kc * 32 + g * 8];
#pragma unroll
            for (int ni = 0; ni < NI; ++ni)
                b[ni][kc] = *(const short8*)&Bsh[(wn * NI * 16 + ni * 16 + c) * 64 + kc * 32 + g * 8];
        }
#pragma unroll
        for (int kc = 0; kc < 2; ++kc)
#pragma unroll
            for (int mi = 0; mi < MI; ++mi)
#pragma unroll
                for (int ni = 0; ni < NI; ++ni)
                    acc[mi][ni] = __builtin_amdgcn_mfma_f32_16x16x32_bf16(
                        a[mi][kc], b[ni][kc], acc[mi][ni], 0, 0, 0);
    }

#pragma unroll
    for (int mi = 0; mi < MI; ++mi)
#pragma unroll
        for (int ni = 0; ni < NI; ++ni)
#pragma unroll
            for (int r = 0; r < 4; ++r) {
                size_t m = m0 + wm * (MI * 16) + mi * 16 + g * 4 + r;
                size_t n = n0 + wn * (NI * 16) + ni * 16 + c;
                float v = acc[mi][ni][r];
                if (bias)  v += bias[n];
                if (resid) v += resid[m * N + n];
                if (relu)  v = fmaxf(v, 0.f);
                if (Cf) Cf[m * N + n] = v;
                if (Cb) Cb[m * N + n] = f2bf(v);
            }
}

// ---------------------------------------------------------------------------
// Fused flash attention + full heatmap. Swapped-operand QK^T (lane owns one
// s-row). Causal phase: 1 barrier/tile (dbuf V, reg-prefetch, diagonal-only
// mask). Score-only phase: barrier-free streaming. 1D grid 512 blocks,
// XCD-chunked: xcd = id&7 gets hb = (xcd<<1)|(k>>5) -> per-XCD K/V locality.
// ---------------------------------------------------------------------------
__global__ __launch_bounds__(256) void attn_kernel(
    const short* __restrict__ QKV,
    float* __restrict__ heat,
    short* __restrict__ wv)
{
    constexpr int S = 2048, LD = 1536;
    __shared__ short Vt[2][64][72];    // [buf][v][t]
    __shared__ short Pl[4][16][72];    // per-wave P, [s][t]

    int tid = threadIdx.x, wid = tid >> 6, lane = tid & 63;
    int g = lane >> 4, c = lane & 15, g4 = g * 4;
    int id = blockIdx.x;
    int xcd = id & 7, k = id >> 3;           // same hb -> same XCD (heuristic)
    int hb = (xcd << 1) | (k >> 5);
    int sb = k & 31;
    int by = (sb & 1) ? (31 - (sb >> 1)) : (sb >> 1);   // pair (k, 31-k)
    int h = hb >> 1, b = hb & 1;
    int s0 = by * 64, sbase = s0 + wid * 16, sglob = sbase + c;

    const short* qp = QKV + (size_t)(b * S + sglob) * LD + h * 64 + g * 8;
    short8 q0 = *(const short8*)qp, q1 = *(const short8*)(qp + 32);

    f32x4 o[4];
#pragma unroll
    for (int ni = 0; ni < 4; ++ni) o[ni] = (f32x4){0.f, 0.f, 0.f, 0.f};
    float m_run = -1e30f, l_run = 0.f;

    const short* kb_base = QKV + (size_t)b * S * LD + 512 + h * 64;
    int vrow = tid >> 2, vch = tid & 3;
    const short* vb_base = QKV + (size_t)b * S * LD + 1024 + h * 64 + vch * 16;

    auto loadK = [&](int tt, short8 dst[4][2]) {
#pragma unroll
        for (int ni = 0; ni < 4; ++ni)
#pragma unroll
            for (int kc = 0; kc < 2; ++kc)
                dst[ni][kc] = *(const short8*)(kb_base +
                    (size_t)(tt * 64 + ni * 16 + c) * LD + kc * 32 + g * 8);
    };

    short8 kcur[4][2];
    loadK(0, kcur);
    short8 va, vb2;
    {
        const short* vp = vb_base + (size_t)vrow * LD;
        va = *(const short8*)vp; vb2 = *(const short8*)(vp + 8);
    }

    // ---- causal phase: tiles 0..by, 1 barrier/tile ----
    for (int tt = 0; tt <= by; ++tt) {
        int cur = tt & 1;
        // write V(tt) regs -> LDS (safe: readers of this buf were two
        // iterations ago, separated by last iteration's barrier)
#pragma unroll
        for (int j = 0; j < 8; ++j) Vt[cur][vch * 16 + j][vrow] = va[j];
#pragma unroll
        for (int j = 0; j < 8; ++j) Vt[cur][vch * 16 + 8 + j][vrow] = vb2[j];

        short8 knext[4][2], vna, vnb;
        if (tt < 31) loadK(tt + 1, knext);
        if (tt < by) {
            const short* vp = vb_base + (size_t)((tt + 1) * 64 + vrow) * LD;
            vna = *(const short8*)vp; vnb = *(const short8*)(vp + 8);
        }

        int t0 = tt * 64;
        f32x4 sacc[4];
#pragma unroll
        for (int ni = 0; ni < 4; ++ni) {
            sacc[ni] = (f32x4){0.f, 0.f, 0.f, 0.f};
            sacc[ni] = __builtin_amdgcn_mfma_f32_16x16x32_bf16(kcur[ni][0], q0, sacc[ni], 0, 0, 0);
            sacc[ni] = __builtin_amdgcn_mfma_f32_16x16x32_bf16(kcur[ni][1], q1, sacc[ni], 0, 0, 0);
        }
#pragma unroll
        for (int ni = 0; ni < 4; ++ni)
            __builtin_nontemporal_store(sacc[ni],
                (f32x4*)&heat[((size_t)hb * S + sglob) * S + t0 + ni * 16 + g4]);

        float tm = -1e30f;
        if (tt == by) {   // diagonal tile: mask
#pragma unroll
            for (int ni = 0; ni < 4; ++ni)
#pragma unroll
                for (int r = 0; r < 4; ++r) {
                    int t = t0 + ni * 16 + g4 + r;
                    float v = (t <= sglob) ? sacc[ni][r] : -1e30f;
                    sacc[ni][r] = v;
                    tm = fmaxf(tm, v);
                }
        } else {          // interior: fully causal
#pragma unroll
            for (int ni = 0; ni < 4; ++ni)
#pragma unroll
                for (int r = 0; r < 4; ++r)
                    tm = fmaxf(tm, sacc[ni][r]);
        }
        tm = fmaxf(tm, __shfl_xor(tm, 16));
        tm = fmaxf(tm, __shfl_xor(tm, 32));

        float mn = fmaxf(m_run, tm);
        float sc = __expf(m_run - mn);
        m_run = mn;
        float ps = 0.f;
#pragma unroll
        for (int ni = 0; ni < 4; ++ni)
#pragma unroll
            for (int r = 0; r < 4; ++r) {
                float p = __expf(sacc[ni][r] - mn);
                sacc[ni][r] = p;
                ps += p;
            }
        ps += __shfl_xor(ps, 16);
        ps += __shfl_xor(ps, 32);
        l_run = l_run * sc + ps;

        float scr[4];
#pragma unroll
        for (int r = 0; r < 4; ++r) scr[r] = __shfl(sc, g4 + r, 64);
#pragma unroll
        for (int ni = 0; ni < 4; ++ni)
#pragma unroll
            for (int r = 0; r < 4; ++r)
                o[ni][r] *= scr[r];

        // P (bf16) to wave-local LDS: lane owns row s=c, contiguous t
#pragma unroll
        for (int ni = 0; ni < 4; ++ni) {
            short4 pw;
            pw.x = f2bf(sacc[ni][0]); pw.y = f2bf(sacc[ni][1]);
            pw.z = f2bf(sacc[ni][2]); pw.w = f2bf(sacc[ni][3]);
            *reinterpret_cast<short4*>(&Pl[wid][c][ni * 16 + g4]) = pw;
        }

        __syncthreads();   // Vt[cur] fully written by all waves

        short8 pa0 = *reinterpret_cast<const short8*>(&Pl[wid][c][g * 8]);
        short8 pa1 = *reinterpret_cast<const short8*>(&Pl[wid][c][32 + g * 8]);
#pragma unroll
        for (int ni = 0; ni < 4; ++ni) {
            short8 vb0 = *reinterpret_cast<const short8*>(&Vt[cur][ni * 16 + c][g * 8]);
            short8 vb1 = *reinterpret_cast<const short8*>(&Vt[cur][ni * 16 + c][32 + g * 8]);
            o[ni] = __builtin_amdgcn_mfma_f32_16x16x32_bf16(pa0, vb0, o[ni], 0, 0, 0);
            o[ni] = __builtin_amdgcn_mfma_f32_16x16x32_bf16(pa1, vb1, o[ni], 0, 0, 0);
        }

        if (tt < 31) {
#pragma unroll
            for (int ni = 0; ni < 4; ++ni)
#pragma unroll
                for (int kc = 0; kc < 2; ++kc)
                    kcur[ni][kc] = knext[ni][kc];
        }
        if (tt < by) { va = vna; vb2 = vnb; }
    }

    // ---- score-only phase: barrier-free streaming ----
    for (int tt = by + 1; tt < 32; ++tt) {
        int t0 = tt * 64;
        short8 knext[4][2];
        if (tt < 31) loadK(tt + 1, knext);
        f32x4 sacc[4];
#pragma unroll
        for (int ni = 0; ni < 4; ++ni) {
            sacc[ni] = (f32x4){0.f, 0.f, 0.f, 0.f};
            sacc[ni] = __builtin_amdgcn_mfma_f32_16x16x32_bf16(kcur[ni][0], q0, sacc[ni], 0, 0, 0);
            sacc[ni] = __builtin_amdgcn_mfma_f32_16x16x32_bf16(kcur[ni][1], q1, sacc[ni], 0, 0, 0);
        }
#pragma unroll
        for (int ni = 0; ni < 4; ++ni)
            __builtin_nontemporal_store(sacc[ni],
                (f32x4*)&heat[((size_t)hb * S + sglob) * S + t0 + ni * 16 + g4]);
        if (tt < 31) {
#pragma unroll
            for (int ni = 0; ni < 4; ++ni)
#pragma unroll
                for (int kc = 0; kc < 2; ++kc)
                    kcur[ni][kc] = knext[ni][kc];
        }
    }

    float linv[4];
#pragma unroll
    for (int r = 0; r < 4; ++r) linv[r] = 1.0f / __shfl(l_run, g4 + r, 64);
#pragma unroll
    for (int ni = 0; ni < 4; ++ni)
#pragma unroll
        for (int r = 0; r < 4; ++r) {
            float v = o[ni][r] * linv[r];
            wv[(size_t)(b * S + sbase + g4 + r) * 512 + h * 64 + ni * 16 + c] = f2bf(v);
        }
}

// ---------------------------------------------------------------------------
// LayerNorm over last dim 512; optional secondary bf16 output.
// ---------------------------------------------------------------------------
__device__ __forceinline__ float block_sum256(float v, float* sm) {
#pragma unroll
    for (int off = 32; off; off >>= 1) v += __shfl_down(v, off);
    __syncthreads();
    if ((threadIdx.x & 63) == 0) sm[threadIdx.x >> 6] = v;
    __syncthreads();
    return sm[0] + sm[1] + sm[2] + sm[3];
}

__global__ __launch_bounds__(256) void ln_kernel(
    const float* __restrict__ in, const float* __restrict__ g,
    const float* __restrict__ bta, float* __restrict__ outf,
    short* __restrict__ outb)
{
    __shared__ float sm[4];
    int row = blockIdx.x, tid = threadIdx.x;
    const float* r = in + (size_t)row * 512;
    float v0 = r[tid], v1 = r[tid + 256];
    float mu = block_sum256(v0 + v1, sm) * (1.f / 512.f);
    float d0 = v0 - mu, d1 = v1 - mu;
    float var = block_sum256(d0 * d0 + d1 * d1, sm) * (1.f / 512.f);
    float rs = rsqrtf(var + 1e-5f);
    float o0 = d0 * rs * g[tid] + bta[tid];
    float o1 = d1 * rs * g[tid + 256] + bta[tid + 256];
    outf[(size_t)row * 512 + tid]       = o0;
    outf[(size_t)row * 512 + tid + 256] = o1;
    if (outb) {
        outb[(size_t)row * 512 + tid]       = f2bf(o0);
        outb[(size_t)row * 512 + tid + 256] = f2bf(o1);
    }
}

// ---------------------------------------------------------------------------
extern "C" void kernel_launch(void* const* d_in, const int* in_sizes, int n_in,
                              void* d_out, int out_size, void* d_ws, size_t ws_size,
                              hipStream_t stream)
{
    const float* x    = (const float*)d_in[0];
    const float* Wq   = (const float*)d_in[1];
    const float* bq   = (const float*)d_in[2];
    const float* Wk   = (const float*)d_in[3];
    const float* bk   = (const float*)d_in[4];
    const float* Wv   = (const float*)d_in[5];
    const float* bv   = (const float*)d_in[6];
    const float* Wo   = (const float*)d_in[7];
    const float* bo   = (const float*)d_in[8];
    const float* W1   = (const float*)d_in[9];
    const float* b1   = (const float*)d_in[10];
    const float* W2   = (const float*)d_in[11];
    const float* b2   = (const float*)d_in[12];
    const float* ln1g = (const float*)d_in[13];
    const float* ln1b = (const float*)d_in[14];
    const float* ln2g = (const float*)d_in[15];
    const float* ln2b = (const float*)d_in[16];

    const int T = 4096;

    char* w = (char*)d_ws;
    short* xb     = (short*)(w);                     // 4096x512 bf16
    short* QKVb   = (short*)(w + 4194304);           // 4096x1536 bf16
    short* wvb    = (short*)(w + 16777216);          // 4096x512 bf16
    float* tmpf   = (float*)(w + 20971520);          // 4096x512 f32
    float* x1f    = (float*)(w + 29360128);          // 4096x512 f32
    short* x1b    = (short*)(w + 37748736);          // 4096x512 bf16
    short* Wqkv_t = (short*)(w + 41943040);          // 1536x512 bf16
    short* Wo_t   = (short*)(w + 43515904);          // 512x512 bf16
    short* W1_t   = (short*)(w + 44040192);          // 2048x512 bf16
    short* W2_t   = (short*)(w + 46137344);          // 512x2048 bf16
    float* qbias  = (float*)(w + 48234496);          // 1536 f32
    short* hidb   = (short*)(w);                     // 4096x2048 bf16 (aliases xb+QKVb, dead then)

    float* out_x2 = (float*)d_out;
    float* heat   = out_x2 + (size_t)T * 512;

    prep_kernel<<<dim3(5126), 256, 0, stream>>>(
        x, xb, Wq, Wk, Wv, Wo, W1, W2,
        Wqkv_t, Wo_t, W1_t, W2_t, bq, bk, bv, qbias);

    // QKV projection (combined, N=1536)
    gemm2<2, 4><<<dim3(64, 12), 256, 0, stream>>>(
        xb, 512, Wqkv_t, 512, qbias, nullptr, nullptr, QKVb, 1536, 512, 0);

    // fused attention + heatmap
    attn_kernel<<<dim3(512), 256, 0, stream>>>(QKVb, heat, wvb);

    // Wo projection + residual
    gemm2<2, 2><<<dim3(64, 8), 256, 0, stream>>>(
        wvb, 512, Wo_t, 512, bo, x, tmpf, nullptr, 512, 512, 0);
    ln_kernel<<<dim3(T), 256, 0, stream>>>(tmpf, ln1g, ln1b, x1f, x1b);

    // FFN
    gemm2<2, 4><<<dim3(64, 16), 256, 0, stream>>>(
        x1b, 512, W1_t, 512, b1, nullptr, nullptr, hidb, 2048, 512, 1);
    gemm2<2, 2><<<dim3(64, 8), 256, 0, stream>>>(
        hidb, 2048, W2_t, 2048, b2, x1f, tmpf, nullptr, 512, 2048, 0);
    ln_kernel<<<dim3(T), 256, 0, stream>>>(tmpf, ln2g, ln2b, out_x2, nullptr);
}